// Round 1
// baseline (99.949 us; speedup 1.0000x reference)
//
#include <hip/hip_runtime.h>

// PS-RoIAlign forward, fp32.
// input  [N=8, C=490, H=100, W=100]
// rois   [K=2048, 5]  (batch_idx, x1, y1, x2, y2) in image space
// out    [K, Cout=10, PH=7, PW=7]
//
// Position-sensitive mapping: output (cout, ph, pw) reads channel
// c = cout*49 + ph*7 + pw  ==  (flat output idx) % 490.
// One thread per output element; S = SR*SR = 4 samples, 16 gathers.

#define PSR_PH 7
#define PSR_PW 7
#define PSR_SCALE 0.0625f

__global__ __launch_bounds__(256) void PSRoIAlign_72069551227028_kernel(
    const float* __restrict__ input,
    const float* __restrict__ rois,
    float* __restrict__ out,
    int total)
{
    const int C = 490, H = 100, W = 100;

    int tid = blockIdx.x * blockDim.x + threadIdx.x;
    if (tid >= total) return;

    int k = tid / C;
    int c = tid - k * C;           // channel = cout*49 + ph*7 + pw
    int s = c % 49;
    int ph = s / 7;
    int pw = s - ph * 7;

    const float* r = rois + (size_t)k * 5;
    int   b  = (int)r[0];
    float sw = r[1] * PSR_SCALE - 0.5f;
    float sh = r[2] * PSR_SCALE - 0.5f;
    float ew = r[3] * PSR_SCALE - 0.5f;
    float eh = r[4] * PSR_SCALE - 0.5f;
    float roi_w = fmaxf(ew - sw, 0.1f);
    float roi_h = fmaxf(eh - sh, 0.1f);
    float bin_h = roi_h * (1.0f / PSR_PH);
    float bin_w = roi_w * (1.0f / PSR_PW);

    const float* base = input + ((size_t)b * C + c) * (size_t)(H * W);

    // Per-axis bilinear params for the 2 sample offsets (SR=2: 0.25, 0.75).
    int   yl[2], yh[2];  float fy[2];  bool yv[2];
    int   xl[2], xh[2];  float fx[2];  bool xv[2];
#pragma unroll
    for (int i = 0; i < 2; ++i) {
        float off = (i + 0.5f) * 0.5f;

        float y = sh + ((float)ph + off) * bin_h;
        yv[i] = (y >= -1.0f) && (y <= (float)H);
        float cy = fmaxf(y, 0.0f);
        int lo = min((int)cy, H - 1);      // floor(cy) since cy >= 0
        yl[i] = lo;
        yh[i] = min(lo + 1, H - 1);
        if (lo >= H - 1) cy = (float)lo;   // frac -> 0 at the top edge
        fy[i] = cy - (float)lo;

        float x = sw + ((float)pw + off) * bin_w;
        xv[i] = (x >= -1.0f) && (x <= (float)W);
        float cx = fmaxf(x, 0.0f);
        int lox = min((int)cx, W - 1);
        xl[i] = lox;
        xh[i] = min(lox + 1, W - 1);
        if (lox >= W - 1) cx = (float)lox;
        fx[i] = cx - (float)lox;
    }

    float acc = 0.0f;
#pragma unroll
    for (int iy = 0; iy < 2; ++iy) {
#pragma unroll
        for (int ix = 0; ix < 2; ++ix) {
            if (yv[iy] && xv[ix]) {
                float ly = fy[iy], lx = fx[ix];
                float hy = 1.0f - ly, hx = 1.0f - lx;
                const float* py0 = base + yl[iy] * W;
                const float* py1 = base + yh[iy] * W;
                float v = py0[xl[ix]] * (hy * hx)
                        + py0[xh[ix]] * (hy * lx)
                        + py1[xl[ix]] * (ly * hx)
                        + py1[xh[ix]] * (ly * lx);
                acc += v;
            }
        }
    }
    out[tid] = acc * 0.25f;
}

extern "C" void kernel_launch(void* const* d_in, const int* in_sizes, int n_in,
                              void* d_out, int out_size, void* d_ws, size_t ws_size,
                              hipStream_t stream) {
    const float* input = (const float*)d_in[0];
    const float* rois  = (const float*)d_in[1];
    float* out = (float*)d_out;

    int total = out_size;  // K * Cout * PH * PW = 2048*10*7*7
    int block = 256;
    int grid = (total + block - 1) / block;
    PSRoIAlign_72069551227028_kernel<<<grid, block, 0, stream>>>(input, rois, out, total);
}

// Round 2
// 55.755 us; speedup vs baseline: 1.7926x; 1.7926x over previous
//
#include <hip/hip_runtime.h>

// PS-RoIAlign forward, fp32 — L2-locality (channel-major, XCD-pinned) version.
//
// input  [N=8, C=490, H=100, W=100]   (157 MB)
// rois   [K=2048, 5]
// out    [K, Cout=10, PH=7, PW=7]  -> flat out[k*490 + c], c = cout*49+ph*7+pw
//
// Work decomposition:
//   - persistent grid of 512 blocks x 256 threads (all co-resident: 2 blk/CU)
//   - xcd  = blockIdx % 8   (HW round-robins blocks across the 8 XCDs)
//   - slot = blockIdx / 8 in [0,64): j = slot>>3 channel-in-group, rb = slot&7
//   - thread's roi k = rb*256 + tid   (fixed for the whole kernel)
//   - g-loop walks channel groups: c = xcd + 8*(g*8 + j), so per phase each
//     XCD touches 8 channels x 8 batches x 40KB = 2.5 MB  (< 4 MB L2)
//
// All 16 bilinear-corner loads are unconditional (indices clamped in-bounds);
// the torchvision validity test becomes a multiplicative 0/1 mask.

#define PSR_K   2048
#define PSR_C   490
#define PSR_H   100
#define PSR_W   100
#define PSR_SC  0.0625f

__global__ __launch_bounds__(256) void PSRoIAlign_72069551227028_kernel(
    const float* __restrict__ input,
    const float* __restrict__ rois,
    float* __restrict__ out)
{
    const int tid  = threadIdx.x;
    const int xcd  = blockIdx.x & 7;
    const int slot = blockIdx.x >> 3;   // 0..63
    const int j    = slot >> 3;         // 0..7  channel-in-group
    const int rb   = slot & 7;          // 0..7  roi block
    const int k    = rb * 256 + tid;    // 0..2047

    // ---- per-roi params: constant across the channel loop ----
    const float* r = rois + k * 5;
    const int   b  = (int)r[0];
    const float sw = r[1] * PSR_SC - 0.5f;
    const float sh = r[2] * PSR_SC - 0.5f;
    const float ew = r[3] * PSR_SC - 0.5f;
    const float eh = r[4] * PSR_SC - 0.5f;
    const float bin_w = fmaxf(ew - sw, 0.1f) * (1.0f / 7.0f);
    const float bin_h = fmaxf(eh - sh, 0.1f) * (1.0f / 7.0f);

    const float* bbase = input + (size_t)b * (PSR_C * PSR_H * PSR_W);

    for (int g = 0; g < 8; ++g) {
        const int m = g * 8 + j;
        const int c = xcd + 8 * m;
        if (c >= PSR_C) break;          // uniform per block (j fixed)

        // channel -> (ph, pw); cout is implicit in c
        const int s49 = c % 49;
        const int ph  = s49 / 7;
        const int pw  = s49 - ph * 7;

        const float* base = bbase + (size_t)c * (PSR_H * PSR_W);

        // ---- per-axis bilinear params, SR=2 offsets {0.25, 0.75} ----
        int   yl[2], yh[2], xl[2], xh[2];
        float fy[2], fx[2], my[2], mx[2];
#pragma unroll
        for (int i = 0; i < 2; ++i) {
            const float off = (i + 0.5f) * 0.5f;

            float y = sh + ((float)ph + off) * bin_h;
            my[i] = (y >= -1.0f && y <= (float)PSR_H) ? 1.0f : 0.0f;
            float cy = fmaxf(y, 0.0f);
            int lo = min((int)cy, PSR_H - 1);
            yl[i] = lo;
            yh[i] = min(lo + 1, PSR_H - 1);
            if (lo >= PSR_H - 1) cy = (float)lo;
            fy[i] = cy - (float)lo;

            float x = sw + ((float)pw + off) * bin_w;
            mx[i] = (x >= -1.0f && x <= (float)PSR_W) ? 1.0f : 0.0f;
            float cx = fmaxf(x, 0.0f);
            int lox = min((int)cx, PSR_W - 1);
            xl[i] = lox;
            xh[i] = min(lox + 1, PSR_W - 1);
            if (lox >= PSR_W - 1) cx = (float)lox;
            fx[i] = cx - (float)lox;
        }

        // ---- 16 unconditional gathers (4 rows x 4 cols) ----
        const float* rp0 = base + yl[0] * PSR_W;
        const float* rp1 = base + yh[0] * PSR_W;
        const float* rp2 = base + yl[1] * PSR_W;
        const float* rp3 = base + yh[1] * PSR_W;
        const int c0 = xl[0], c1 = xh[0], c2 = xl[1], c3 = xh[1];

        float v[16];
        v[ 0] = rp0[c0]; v[ 1] = rp0[c1]; v[ 2] = rp0[c2]; v[ 3] = rp0[c3];
        v[ 4] = rp1[c0]; v[ 5] = rp1[c1]; v[ 6] = rp1[c2]; v[ 7] = rp1[c3];
        v[ 8] = rp2[c0]; v[ 9] = rp2[c1]; v[10] = rp2[c2]; v[11] = rp2[c3];
        v[12] = rp3[c0]; v[13] = rp3[c1]; v[14] = rp3[c2]; v[15] = rp3[c3];

        // ---- weighted accumulate, validity as multiplicative mask ----
        float acc = 0.0f;
#pragma unroll
        for (int iy = 0; iy < 2; ++iy) {
            const float ly = fy[iy], hy = 1.0f - fy[iy];
#pragma unroll
            for (int ix = 0; ix < 2; ++ix) {
                const float lx = fx[ix], hx = 1.0f - fx[ix];
                const float msk = my[iy] * mx[ix];
                const int rlo = iy * 8;          // row pair base in v[]
                const int cb  = ix * 2;          // col pair base
                const float samp =
                      v[rlo + cb    ] * (hy * hx)
                    + v[rlo + cb + 1] * (hy * lx)
                    + v[rlo + 4 + cb    ] * (ly * hx)
                    + v[rlo + 4 + cb + 1] * (ly * lx);
                acc += msk * samp;
            }
        }

        out[k * PSR_C + c] = acc * 0.25f;
    }
}

extern "C" void kernel_launch(void* const* d_in, const int* in_sizes, int n_in,
                              void* d_out, int out_size, void* d_ws, size_t ws_size,
                              hipStream_t stream) {
    const float* input = (const float*)d_in[0];
    const float* rois  = (const float*)d_in[1];
    float* out = (float*)d_out;

    PSRoIAlign_72069551227028_kernel<<<512, 256, 0, stream>>>(input, rois, out);
}

// Round 3
// 41.022 us; speedup vs baseline: 2.4365x; 1.3592x over previous
//
#include <hip/hip_runtime.h>

// PS-RoIAlign forward, fp32 — round 3.
//  - 1024 blocks x 256 threads (4 blk/CU, 16 waves/CU, fully co-resident)
//  - XCD-chunked channels: XCD x owns c in [x*64, x*64+64); thread owns 4
//    consecutive channels -> staged 2x8B stores (kills write-allocate blowup)
//  - phase-blocked reads: at a given g, XCD touches 16 channels x 8 batches
//    x 40KB = 5 MB (~L2), preserving round-2's FETCH win
//  - paired 8B gathers: x-corners are adjacent; 8 loads/channel instead of 16
//    (weight-swap trick keeps the W-1 clamp edge exact and in-bounds)
//
// input [8,490,100,100] fp32, rois [2048,5], out [2048,490] (=K,Cout,7,7)

#define PSR_C  490
#define PSR_H  100
#define PSR_W  100
#define PSR_SC 0.0625f

struct F2 { float x, y; };

__device__ __forceinline__ F2 ld2(const float* p) {
    F2 v;
    __builtin_memcpy(&v, p, sizeof(F2));   // 4B-aligned 8B load
    return v;
}

__global__ __launch_bounds__(256) void PSRoIAlign_72069551227028_kernel(
    const float* __restrict__ input,
    const float* __restrict__ rois,
    float* __restrict__ out)
{
    const int tid  = threadIdx.x;
    const int xcd  = blockIdx.x & 7;    // HW round-robins blocks over 8 XCDs
    const int slot = blockIdx.x >> 3;   // 0..127
    const int j    = slot >> 3;         // 0..15 channel-quad within XCD chunk
    const int rb   = slot & 7;          // 0..7  roi block
    const int k    = rb * 256 + tid;    // 0..2047
    const int cb   = xcd * 64 + j * 4;  // first of this thread's 4 channels

    if (cb >= PSR_C) return;            // uniform per block

    // ---- per-roi params (fixed for the whole thread) ----
    const float* r = rois + k * 5;
    const int   b  = (int)r[0];
    const float sw = r[1] * PSR_SC - 0.5f;
    const float sh = r[2] * PSR_SC - 0.5f;
    const float ew = r[3] * PSR_SC - 0.5f;
    const float eh = r[4] * PSR_SC - 0.5f;
    const float bin_w = fmaxf(ew - sw, 0.1f) * (1.0f / 7.0f);
    const float bin_h = fmaxf(eh - sh, 0.1f) * (1.0f / 7.0f);

    const float* bb = input + (size_t)b * (PSR_C * PSR_H * PSR_W);

    float acc[4];
#pragma unroll
    for (int g = 0; g < 4; ++g) {
        acc[g] = 0.0f;
        const int c = cb + g;
        if (c >= PSR_C) continue;       // uniform (only cb==488 tail)

        const int s49 = c % 49;
        const int ph  = s49 / 7;
        const int pw  = s49 - ph * 7;
        const float* base = bb + (size_t)c * (PSR_H * PSR_W);

        // ---- per-axis bilinear params, SR=2 offsets {0.25, 0.75} ----
        int   yb[2], xb[2];
        float wyl[2], wyh[2], wxl[2], wxh[2], msky[2], mskx[2];
#pragma unroll
        for (int i = 0; i < 2; ++i) {
            const float off = (i + 0.5f) * 0.5f;

            float y = sh + ((float)ph + off) * bin_h;
            msky[i] = (y >= -1.0f && y <= (float)PSR_H) ? 1.0f : 0.0f;
            float cy = fmaxf(y, 0.0f);
            int lo = min((int)cy, PSR_H - 1);
            float fr = cy - (float)lo;
            if (lo >= PSR_H - 1) { yb[i] = PSR_H - 2; wyl[i] = 0.0f;      wyh[i] = 1.0f; }
            else                 { yb[i] = lo;        wyl[i] = 1.0f - fr; wyh[i] = fr;   }

            float x = sw + ((float)pw + off) * bin_w;
            mskx[i] = (x >= -1.0f && x <= (float)PSR_W) ? 1.0f : 0.0f;
            float cx = fmaxf(x, 0.0f);
            int lox = min((int)cx, PSR_W - 1);
            float frx = cx - (float)lox;
            if (lox >= PSR_W - 1) { xb[i] = PSR_W - 2; wxl[i] = 0.0f;       wxh[i] = 1.0f; }
            else                  { xb[i] = lox;       wxl[i] = 1.0f - frx; wxh[i] = frx;  }
        }

        // ---- 8 paired 8B gathers: [iy][ix] x {row lo, row hi} ----
        F2 v[2][2][2];
#pragma unroll
        for (int iy = 0; iy < 2; ++iy)
#pragma unroll
            for (int ix = 0; ix < 2; ++ix) {
                const float* p = base + yb[iy] * PSR_W + xb[ix];
                v[iy][ix][0] = ld2(p);
                v[iy][ix][1] = ld2(p + PSR_W);
            }

        // ---- weighted accumulate, validity as multiplicative mask ----
#pragma unroll
        for (int iy = 0; iy < 2; ++iy)
#pragma unroll
            for (int ix = 0; ix < 2; ++ix) {
                float v0 = v[iy][ix][0].x * wxl[ix] + v[iy][ix][0].y * wxh[ix];
                float v1 = v[iy][ix][1].x * wxl[ix] + v[iy][ix][1].y * wxh[ix];
                acc[g] += (msky[iy] * mskx[ix]) * (wyl[iy] * v0 + wyh[iy] * v1);
            }
    }

    // ---- staged store: 4 contiguous channels (tail quad has 2 valid) ----
    float* o = out + (size_t)k * PSR_C + cb;
    if (cb + 4 <= PSR_C) {
        F2 a { acc[0] * 0.25f, acc[1] * 0.25f };
        F2 c2{ acc[2] * 0.25f, acc[3] * 0.25f };
        __builtin_memcpy(o,     &a,  sizeof(F2));
        __builtin_memcpy(o + 2, &c2, sizeof(F2));
    } else {                                  // cb == 488
        F2 a { acc[0] * 0.25f, acc[1] * 0.25f };
        __builtin_memcpy(o, &a, sizeof(F2));
    }
}

extern "C" void kernel_launch(void* const* d_in, const int* in_sizes, int n_in,
                              void* d_out, int out_size, void* d_ws, size_t ws_size,
                              hipStream_t stream) {
    const float* input = (const float*)d_in[0];
    const float* rois  = (const float*)d_in[1];
    float* out = (float*)d_out;

    PSRoIAlign_72069551227028_kernel<<<1024, 256, 0, stream>>>(input, rois, out);
}

// Round 4
// 29.971 us; speedup vs baseline: 3.3349x; 1.3687x over previous
//
#include <hip/hip_runtime.h>

// PS-RoIAlign forward, fp32 — round 4: windowed x-loads.
//
// Round-3 diagnosis: ~8M scattered 8B gathers = ~10 L2 requests/cyc/XCD ->
// L2 request-rate bound. Fix: the two x-samples of a bin are <=2.14 px apart
// (roi_w <= 30 feature px, bin_w <= 4.29, dx = bin_w/2), so xb1-xb0 <= 3.
// One 16B window per row covers both x corner-pairs when e1 <= 2 (common);
// rare e1==3 lanes take an exec-masked extra 8B load. 8 -> ~4 requests per
// (roi, channel).
//
// input [8,490,100,100] fp32, rois [2048,5], out [2048,490]

#define PSR_C  490
#define PSR_H  100
#define PSR_W  100
#define PSR_SC 0.0625f

typedef float f4v __attribute__((ext_vector_type(4), aligned(4)));
typedef float f2v __attribute__((ext_vector_type(2), aligned(4)));

__device__ __forceinline__ f4v ld4(const float* p) { return *(const f4v*)p; }
__device__ __forceinline__ f2v ld2(const float* p) { return *(const f2v*)p; }

// select element e (0..2) / e+1 from a 4-wide window
__device__ __forceinline__ float sel3(float a0, float a1, float a2, int e) {
    float r = (e == 1) ? a1 : a0;
    return (e == 2) ? a2 : r;
}

__global__ __launch_bounds__(256) void PSRoIAlign_72069551227028_kernel(
    const float* __restrict__ input,
    const float* __restrict__ rois,
    float* __restrict__ out)
{
    const int tid  = threadIdx.x;
    const int xcd  = blockIdx.x & 7;
    const int slot = blockIdx.x >> 3;   // 0..127
    const int j    = slot >> 3;         // 0..15 channel-quad within XCD chunk
    const int rb   = slot & 7;          // 0..7  roi block
    const int k    = rb * 256 + tid;    // 0..2047
    const int cb   = xcd * 64 + j * 4;  // first of this thread's 4 channels

    if (cb >= PSR_C) return;            // uniform per block

    // ---- per-roi params ----
    const float* r = rois + k * 5;
    const int   b  = (int)r[0];
    const float sw = r[1] * PSR_SC - 0.5f;
    const float sh = r[2] * PSR_SC - 0.5f;
    const float ew = r[3] * PSR_SC - 0.5f;
    const float eh = r[4] * PSR_SC - 0.5f;
    const float bin_w = fmaxf(ew - sw, 0.1f) * (1.0f / 7.0f);
    const float bin_h = fmaxf(eh - sh, 0.1f) * (1.0f / 7.0f);

    const float* bb = input + (size_t)b * (PSR_C * PSR_H * PSR_W);

    float acc[4];
#pragma unroll
    for (int g = 0; g < 4; ++g) {
        acc[g] = 0.0f;
        const int c = cb + g;
        if (c >= PSR_C) continue;       // uniform (cb==488 tail only)

        const int s49 = c % 49;
        const int ph  = s49 / 7;
        const int pw  = s49 - ph * 7;
        const float* base = bb + (size_t)c * (PSR_H * PSR_W);

        // ---- y params (2 samples, weight-swap at the H-1 edge) ----
        int   yb[2];
        float wyl[2], wyh[2], msky[2];
        // ---- x params ----
        int   xb[2];
        float wxl[2], wxh[2], mskx[2];
#pragma unroll
        for (int i = 0; i < 2; ++i) {
            const float off = (i + 0.5f) * 0.5f;

            float y = sh + ((float)ph + off) * bin_h;
            msky[i] = (y >= -1.0f && y <= (float)PSR_H) ? 1.0f : 0.0f;
            float cy = fmaxf(y, 0.0f);
            int lo = min((int)cy, PSR_H - 1);
            float fr = cy - (float)lo;
            if (lo >= PSR_H - 1) { yb[i] = PSR_H - 2; wyl[i] = 0.0f;      wyh[i] = 1.0f; }
            else                 { yb[i] = lo;        wyl[i] = 1.0f - fr; wyh[i] = fr;   }

            float x = sw + ((float)pw + off) * bin_w;
            mskx[i] = (x >= -1.0f && x <= (float)PSR_W) ? 1.0f : 0.0f;
            float cx = fmaxf(x, 0.0f);
            int lox = min((int)cx, PSR_W - 1);
            float frx = cx - (float)lox;
            if (lox >= PSR_W - 1) { xb[i] = PSR_W - 2; wxl[i] = 0.0f;       wxh[i] = 1.0f; }
            else                  { xb[i] = lox;       wxl[i] = 1.0f - frx; wxh[i] = frx;  }
        }

        // ---- windowed loads: one 16B per row covers both x samples ----
        const int xs = min(xb[0], PSR_W - 4);   // keep window in-row
        const int e0 = xb[0] - xs;              // 0..2
        const int e1 = xb[1] - xs;              // 0..3 (3 is rare)
        const bool far = (e1 > 2);

        const float* r0 = base + yb[0] * PSR_W;
        const float* r2 = base + yb[1] * PSR_W;
        f4v w0 = ld4(r0 + xs);
        f4v w1 = ld4(r0 + PSR_W + xs);
        f4v w2 = ld4(r2 + xs);
        f4v w3 = ld4(r2 + PSR_W + xs);

        f2v ex0 = {0.f, 0.f}, ex1 = ex0, ex2 = ex0, ex3 = ex0;
        if (far) {                               // exec-masked; rare lanes only
            ex0 = ld2(r0 + xb[1]);
            ex1 = ld2(r0 + PSR_W + xb[1]);
            ex2 = ld2(r2 + xb[1]);
            ex3 = ld2(r2 + PSR_W + xb[1]);
        }

        // ---- per-row x-interpolation, then y/validity combine ----
        float rv0[4], rv1[4];   // per-row value for sample x0 / x1
        const f4v* wins[4] = { &w0, &w1, &w2, &w3 };
        const f2v* exs[4]  = { &ex0, &ex1, &ex2, &ex3 };
#pragma unroll
        for (int rr = 0; rr < 4; ++rr) {
            f4v w = *wins[rr];
            float s0l = sel3(w.x, w.y, w.z, e0);
            float s0h = sel3(w.y, w.z, w.w, e0);
            float s1l = far ? (*exs[rr]).x : sel3(w.x, w.y, w.z, e1);
            float s1h = far ? (*exs[rr]).y : sel3(w.y, w.z, w.w, e1);
            rv0[rr] = s0l * wxl[0] + s0h * wxh[0];
            rv1[rr] = s1l * wxl[1] + s1h * wxh[1];
        }

#pragma unroll
        for (int iy = 0; iy < 2; ++iy) {
            const int rlo = iy * 2;
            float a0 = wyl[iy] * rv0[rlo] + wyh[iy] * rv0[rlo + 1];   // sample (iy, x0)
            float a1 = wyl[iy] * rv1[rlo] + wyh[iy] * rv1[rlo + 1];   // sample (iy, x1)
            acc[g] += msky[iy] * (mskx[0] * a0 + mskx[1] * a1);
        }
    }

    // ---- staged store: 4 contiguous channels (tail quad has 2 valid) ----
    float* o = out + (size_t)k * PSR_C + cb;
    f2v a { acc[0] * 0.25f, acc[1] * 0.25f };
    *(f2v*)o = a;
    if (cb + 4 <= PSR_C) {
        f2v c2{ acc[2] * 0.25f, acc[3] * 0.25f };
        *(f2v*)(o + 2) = c2;
    }
}

extern "C" void kernel_launch(void* const* d_in, const int* in_sizes, int n_in,
                              void* d_out, int out_size, void* d_ws, size_t ws_size,
                              hipStream_t stream) {
    const float* input = (const float*)d_in[0];
    const float* rois  = (const float*)d_in[1];
    float* out = (float*)d_out;

    PSRoIAlign_72069551227028_kernel<<<1024, 256, 0, stream>>>(input, rois, out);
}

// Round 5
// 29.188 us; speedup vs baseline: 3.4243x; 1.0268x over previous
//
#include <hip/hip_runtime.h>

// PS-RoIAlign forward, fp32 — round 5: max MLP + predicated row loads.
//
// Round-4 diagnosis: latency-bound (req rate 52% of TCC ideal, VALU 5%,
// only 4 loads in flight per wave). Fixes:
//  - two-phase structure: issue ALL window loads for the thread's 4 channels
//    (up to 16x 16B), then consume — 4x memory-level parallelism per wave
//  - predicated row loads: y-samples are <=2.14 rows apart; rows 2/3 load
//    only when distinct (d>=2 / d>=1), else reuse rows 0/1 (~20-25% fewer
//    requests)
//  - far x-sample (e1==3, P~0.5%): low elem is window elem 3; only one extra
//    scalar load per row, lazily at consume
//  - validity masks and the x0.25 mean folded into bilinear weights
//
// input [8,490,100,100] fp32, rois [2048,5], out [2048,490]

#define PSR_C  490
#define PSR_H  100
#define PSR_W  100
#define PSR_HW (PSR_H * PSR_W)
#define PSR_SC 0.0625f

typedef float f4v __attribute__((ext_vector_type(4), aligned(4)));
typedef float f2v __attribute__((ext_vector_type(2), aligned(4)));

__device__ __forceinline__ f4v ld4(const float* p) { return *(const f4v*)p; }

// select element e (0..2) / e+1 from a 4-wide window
__device__ __forceinline__ float sel3(float a0, float a1, float a2, int e) {
    float r = (e == 1) ? a1 : a0;
    return (e == 2) ? a2 : r;
}

__global__ __launch_bounds__(256) void PSRoIAlign_72069551227028_kernel(
    const float* __restrict__ input,
    const float* __restrict__ rois,
    float* __restrict__ out)
{
    const int tid  = threadIdx.x;
    const int xcd  = blockIdx.x & 7;
    const int slot = blockIdx.x >> 3;   // 0..127
    const int j    = slot >> 3;         // 0..15 channel-quad within XCD chunk
    const int rb   = slot & 7;          // 0..7  roi block
    const int k    = rb * 256 + tid;    // 0..2047
    const int cb   = xcd * 64 + j * 4;  // first of this thread's 4 channels
    if (cb >= PSR_C) return;            // uniform per block

    // ---- per-roi params ----
    f4v  rv4 = ld4(rois + k * 5);
    const int   b  = (int)rv4.x;
    const float sw = rv4.y * PSR_SC - 0.5f;
    const float sh = rv4.z * PSR_SC - 0.5f;
    const float ew = rv4.w * PSR_SC - 0.5f;
    const float eh = rois[k * 5 + 4] * PSR_SC - 0.5f;
    const float bin_w = fmaxf(ew - sw, 0.1f) * (1.0f / 7.0f);
    const float bin_h = fmaxf(eh - sh, 0.1f) * (1.0f / 7.0f);

    const float* bb = input + (size_t)b * (PSR_C * PSR_HW);

    // ---- phase 1: params + issue all loads ----
    f4v   w[4][4];                 // [g][row]; rows 2,3 conditionally loaded
    float wx[4][4], wy[4][4];      // x {l0,h0,l1,h1} (mskx folded); y likewise (msky*0.25 folded)
    int   e0a[4], e1a[4], da[4];
    int   o0a[4], o2a[4];          // window row offsets from bb

#pragma unroll
    for (int g = 0; g < 4; ++g) {
        const int c  = cb + g;
        const int cv = (c < PSR_C);
        const int ca = cv ? c : (PSR_C - 1);   // safe addressing for tail quad
        const int s49 = ca % 49;
        const int ph  = s49 / 7;
        const int pw  = s49 - ph * 7;

        int yb[2], xb[2];
#pragma unroll
        for (int i = 0; i < 2; ++i) {
            const float off = (i + 0.5f) * 0.5f;

            float y  = sh + ((float)ph + off) * bin_h;
            float my = (y >= -1.0f && y <= (float)PSR_H) ? 0.25f : 0.0f;  // fold mean/4
            if (!cv) my = 0.0f;
            float cy = fmaxf(y, 0.0f);
            int lo = min((int)cy, PSR_H - 1);
            float fr = cy - (float)lo;
            if (lo >= PSR_H - 1) { yb[i] = PSR_H - 2; wy[g][2*i] = 0.0f;             wy[g][2*i+1] = my;      }
            else                 { yb[i] = lo;        wy[g][2*i] = my * (1.0f - fr); wy[g][2*i+1] = my * fr; }

            float x  = sw + ((float)pw + off) * bin_w;
            float mx = (x >= -1.0f && x <= (float)PSR_W) ? 1.0f : 0.0f;
            float cx = fmaxf(x, 0.0f);
            int lox = min((int)cx, PSR_W - 1);
            float frx = cx - (float)lox;
            if (lox >= PSR_W - 1) { xb[i] = PSR_W - 2; wx[g][2*i] = 0.0f;              wx[g][2*i+1] = mx;       }
            else                  { xb[i] = lox;       wx[g][2*i] = mx * (1.0f - frx); wx[g][2*i+1] = mx * frx; }
        }

        const int xs = min(xb[0], PSR_W - 4);
        const int d  = yb[1] - yb[0];
        const int o0 = ca * PSR_HW + yb[0] * PSR_W + xs;
        const int o2 = ca * PSR_HW + yb[1] * PSR_W + xs;
        e0a[g] = xb[0] - xs;     // 0..2
        e1a[g] = xb[1] - xs;     // 0..3 (3 rare)
        da[g]  = d;
        o0a[g] = o0;
        o2a[g] = o2;

        w[g][0] = ld4(bb + o0);
        w[g][1] = ld4(bb + o0 + PSR_W);
        if (d >= 2) w[g][2] = ld4(bb + o2);            // exec-masked: row yb1
        if (d >= 1) w[g][3] = ld4(bb + o2 + PSR_W);    // exec-masked: row yb1+1
    }

    // ---- phase 2: consume ----
    float acc[4];
#pragma unroll
    for (int g = 0; g < 4; ++g) {
        const int e0 = e0a[g], e1 = e1a[g], d = da[g];
        const bool far = (e1 > 2);

        f4v w0 = w[g][0], w1 = w[g][1];
        f4v w2 = (d == 0) ? w0 : ((d == 1) ? w1 : w[g][2]);
        f4v w3 = (d == 0) ? w1 : w[g][3];

        float ex[4] = {0.f, 0.f, 0.f, 0.f};
        if (far) {                       // rare; one scalar per row at xs+4
            ex[0] = bb[o0a[g] + 4];
            ex[1] = bb[o0a[g] + PSR_W + 4];
            ex[2] = bb[o2a[g] + 4];
            ex[3] = bb[o2a[g] + PSR_W + 4];
        }

        const f4v wrow[4] = { w0, w1, w2, w3 };
        float rsum[4];                   // wy-weighted row sums
#pragma unroll
        for (int rr = 0; rr < 4; ++rr) {
            const f4v ww = wrow[rr];
            float s0l = sel3(ww.x, ww.y, ww.z, e0);
            float s0h = sel3(ww.y, ww.z, ww.w, e0);
            float s1l = far ? ww.w   : sel3(ww.x, ww.y, ww.z, e1);
            float s1h = far ? ex[rr] : sel3(ww.y, ww.z, ww.w, e1);
            float rv0 = s0l * wx[g][0] + s0h * wx[g][1];
            float rv1 = s1l * wx[g][2] + s1h * wx[g][3];
            rsum[rr] = rv0 + rv1;
        }
        acc[g] = wy[g][0] * rsum[0] + wy[g][1] * rsum[1]
               + wy[g][2] * rsum[2] + wy[g][3] * rsum[3];
    }

    // ---- staged store: 4 contiguous channels (tail quad stores 2) ----
    float* o = out + (size_t)k * PSR_C + cb;
    f2v a { acc[0], acc[1] };
    *(f2v*)o = a;
    if (cb + 4 <= PSR_C) {
        f2v c2 { acc[2], acc[3] };
        *(f2v*)(o + 2) = c2;
    }
}

extern "C" void kernel_launch(void* const* d_in, const int* in_sizes, int n_in,
                              void* d_out, int out_size, void* d_ws, size_t ws_size,
                              hipStream_t stream) {
    const float* input = (const float*)d_in[0];
    const float* rois  = (const float*)d_in[1];
    float* out = (float*)d_out;

    PSRoIAlign_72069551227028_kernel<<<1024, 256, 0, stream>>>(input, rois, out);
}